// Round 10
// baseline (396.695 us; speedup 1.0000x reference)
//
#include <hip/hip_runtime.h>

#define Nn 50000
#define Ee 800000
#define INF_ 256
#define HID 128
#define NC 40
#define CAPD 48      // adj_dst row capacity (Poisson(16) tail @48 ~1e-11)
#define CAPS 48      // adj_s row capacity (u-list front, m-list back)
#define LPA_ITERS 10
#define NB 98        // node buckets of 512
#define BSH 9
#define EPB 1024     // edges per bin block
#define NBLK ((Ee + EPB - 1) / EPB)   // 782
#define G1_ROWS 64
#define G1BLK ((Nn + G1_ROWS - 1) / G1_ROWS)  // 782
#define CAPB_D 10240 // per-bucket bin capacity, dst direction (mean 8163)
#define CAPB_S 6144  // per-bucket bin capacity, src/unmasked (mean ~4081)
#define LPA_BLKS ((Nn + 31) / 32)   // 1563
#define SCB 196               // h1b-scale blocks (256 rows each)
// GCN pipeline slices (each carries one LPA iteration in its block-range tail)
#define A1T1 834              // agg1 third 1: nodes [0, 16680)
#define A1T2 833              // agg1 third 2: nodes [16680, 33340)
#define A1T3 833              // agg1 third 3: nodes [33340, 50000)
#define G2H1 79               // gemm2 half 1: rows [0, 25280)
#define G2H2 78               // gemm2 half 2: rows [25280, 50000)
#define AG2H1 782             // agg2 half 1: nodes [0, 25024)
#define AG2H2 781             // agg2 half 2: nodes [25024, 50000)

typedef __attribute__((ext_vector_type(8))) short bfrag;
typedef __attribute__((ext_vector_type(4))) float ffrag;

// ---- bf16 helpers (fp32 math, bf16 storage; RNE rounding) ------------------
__device__ inline unsigned f2bf2(float a, float b) {
    unsigned ua = __float_as_uint(a); ua += 0x7FFFu + ((ua >> 16) & 1u);
    unsigned ub = __float_as_uint(b); ub += 0x7FFFu + ((ub >> 16) & 1u);
    return (ua >> 16) | (ub & 0xFFFF0000u);
}
__device__ inline unsigned short f2bf(float a) {
    unsigned ua = __float_as_uint(a); ua += 0x7FFFu + ((ua >> 16) & 1u);
    return (unsigned short)(ua >> 16);
}
__device__ inline float bf_lo(unsigned u) { return __uint_as_float(u << 16); }
__device__ inline float bf_hi(unsigned u) { return __uint_as_float(u & 0xFFFF0000u); }

__device__ inline bool read_mask(const void* mask, int node, int fmt) {
    if (fmt) return ((const unsigned char*)mask)[node] != 0;
    return ((const int*)mask)[node] != 0;
}

// ---------------------------------------------------------------------------
// detect_prep: mask-format probe (in_sizes is element-count based; device
// probe is load-bearing) + W1 transpose, block-range fused.
__global__ __launch_bounds__(256) void detect_prep(
    const unsigned int* __restrict__ m, int* flag,
    const float* __restrict__ W1, unsigned short* __restrict__ W1t) {
    int bb = blockIdx.x, tid = threadIdx.x;
    if (bb < 49) {
        int i = bb * 256 + tid;
        if (i < 12500) {
            if (m[i] > 1u) atomicOr(flag, 1);
        }
    } else {
        int c = bb - 49;     // 0..127
        W1t[c * INF_ + tid] = f2bf(W1[(size_t)tid * HID + c]);
    }
}

// ---------------------------------------------------------------------------
// phase1: block-range fusion of edge binning + GEMM1 (validated r4: 80us).
__global__ __launch_bounds__(256) void phase1(
    const int* __restrict__ src, const int* __restrict__ dst,
    const void* __restrict__ mask, const int* __restrict__ flag,
    int* __restrict__ cnt_src, int* __restrict__ cur_d, int* __restrict__ cur_s,
    unsigned* __restrict__ bkt_d, unsigned* __restrict__ bkt_s,
    const float* __restrict__ feat, const unsigned short* __restrict__ W1t,
    unsigned short* __restrict__ h1b) {
    __shared__ uint4 smem[784];   // 12544 B, unioned between the two halves
    const int tid = threadIdx.x;
    if (blockIdx.x < NBLK) {
        // ---------------- edge binning half ----------------
        unsigned* stage_d = (unsigned*)smem;          // EPB
        unsigned* stage_s = stage_d + EPB;            // EPB
        int* hd  = (int*)(stage_s + EPB);
        int* od  = hd + NB;                           // NB+1
        int* cd  = od + NB + 1;
        int* gd_ = cd + NB;
        int* hs  = gd_ + NB;
        int* os_ = hs + NB;                           // NB+1
        int* cs_ = os_ + NB + 1;
        int* gs_ = cs_ + NB;
        int lane = tid & 63;
        int wid = tid >> 6;
        int e0 = blockIdx.x * EPB;
        int fmt = *flag;
        if (tid < NB) { hd[tid] = 0; hs[tid] = 0; }
        __syncthreads();                                     // barrier 1

        int rs[EPB / 256], rd[EPB / 256];
        unsigned um = 0;  // bit k: src unmasked
#pragma unroll
        for (int k = 0; k < EPB / 256; k++) {
            int e = e0 + tid + k * 256;
            rs[k] = -1; rd[k] = -1;
            if (e < Ee) {
                int s = src[e], d = dst[e];
                rs[k] = s; rd[k] = d;
                atomicAdd(&cnt_src[s], 1);                   // fire-and-forget
                atomicAdd(&hd[d >> BSH], 1);
                if (!read_mask(mask, s, fmt)) {
                    um |= (1u << k);
                    atomicAdd(&hs[s >> BSH], 1);
                }
            }
        }
        __syncthreads();                                     // barrier 2
        // single-wave exclusive scans: wave 0 -> od, wave 1 -> os_
        if (wid < 2) {
            int* h = wid ? hs : hd;
            int* o = wid ? os_ : od;
            int i0 = lane * 2;
            int v0 = (i0 < NB) ? h[i0] : 0;
            int v1 = (i0 + 1 < NB) ? h[i0 + 1] : 0;
            int s = v0 + v1;
#pragma unroll
            for (int d = 1; d < 64; d <<= 1) {
                int t = __shfl_up(s, d);
                if (lane >= d) s += t;
            }
            int excl = s - v0 - v1;
            if (i0 < NB) o[i0] = excl;
            if (i0 + 1 < NB) o[i0 + 1] = excl + v0;
            if (lane == 63) o[NB] = s;
        }
        __syncthreads();                                     // barrier 3
        if (tid < NB) {
            gd_[tid] = hd[tid] ? atomicAdd(&cur_d[tid], hd[tid]) : 0;
            gs_[tid] = hs[tid] ? atomicAdd(&cur_s[tid], hs[tid]) : 0;
            cd[tid] = od[tid];
            cs_[tid] = os_[tid];
        }
        __syncthreads();                                     // barrier 4
#pragma unroll
        for (int k = 0; k < EPB / 256; k++) {
            if (rd[k] >= 0) {
                int p = atomicAdd(&cd[rd[k] >> BSH], 1);
                stage_d[p] = ((unsigned)rd[k] << 16) | (unsigned)rs[k];
                if (um & (1u << k)) {
                    int q = atomicAdd(&cs_[rs[k] >> BSH], 1);
                    stage_s[q] = ((unsigned)rs[k] << 16) | (unsigned)rd[k];
                }
            }
        }
        __syncthreads();                                     // barrier 5
        // per-bucket writeback: wave w handles buckets w, w+4, ...
        for (int b = wid; b < NB; b += 4) {
            int base = od[b], cntb = hd[b], g0 = gd_[b];
            unsigned* gb = bkt_d + (size_t)b * CAPB_D;
            for (int i = lane; i < cntb; i += 64) {
                int pos = g0 + i;
                if (pos < CAPB_D) gb[pos] = stage_d[base + i];
            }
            int bs = os_[b], cnts = hs[b], gs0 = gs_[b];
            unsigned* gbs = bkt_s + (size_t)b * CAPB_S;
            for (int i = lane; i < cnts; i += 64) {
                int pos = gs0 + i;
                if (pos < CAPB_S) gbs[pos] = stage_s[bs + i];
            }
        }
    } else {
        // ---------------- GEMM1 half (no norm) ----------------
        unsigned short* lA = (unsigned short*)smem;   // [row][k] bf16, 4KB
        unsigned short* lB = lA + G1_ROWS * 32;       // [col][k] bf16, 8KB
        const int row0 = (blockIdx.x - NBLK) * G1_ROWS;
        const int w = tid >> 6;
        const int l = tid & 63;
        const int lane15 = l & 15;
        const int quad = l >> 4;
        const int rw0 = w * 16;

        ffrag acc[8];
#pragma unroll
        for (int t = 0; t < 8; t++) acc[t] = (ffrag){0.f, 0.f, 0.f, 0.f};

        for (int k0 = 0; k0 < INF_; k0 += 32) {
#pragma unroll
            for (int p = 0; p < 2; p++) {
                int idx = tid + p * 256;
                int r = idx >> 3, c4 = idx & 7;
                int grow = row0 + r;
                float4 v = make_float4(0.f, 0.f, 0.f, 0.f);
                if (grow < Nn)
                    v = *(const float4*)(feat + (size_t)grow * INF_ + k0 + c4 * 4);
                uint2 pk;
                pk.x = f2bf2(v.x, v.y);
                pk.y = f2bf2(v.z, v.w);
                *(uint2*)((char*)lA + r * 64 + c4 * 8) = pk;
            }
#pragma unroll
            for (int p = 0; p < 2; p++) {
                int idx = tid + p * 256;
                int col = idx >> 2, q = idx & 3;
                uint4 v = *(const uint4*)((const char*)W1t + col * 512 + k0 * 2 + q * 16);
                *(uint4*)((char*)lB + col * 64 + q * 16) = v;
            }
            __syncthreads();
            int arow = rw0 + lane15;
            bfrag af = *(const bfrag*)((const char*)lA + arow * 64 + quad * 16);
#pragma unroll
            for (int t = 0; t < 8; t++) {
                int col = t * 16 + lane15;
                bfrag bf = *(const bfrag*)((const char*)lB + col * 64 + quad * 16);
                acc[t] = __builtin_amdgcn_mfma_f32_16x16x32_bf16(af, bf, acc[t], 0, 0, 0);
            }
            __syncthreads();
        }
#pragma unroll
        for (int t = 0; t < 8; t++) {
#pragma unroll
            for (int i = 0; i < 4; i++) {
                int grow = row0 + rw0 + quad * 4 + i;
                if (grow < Nn)
                    h1b[(size_t)grow * HID + t * 16 + lane15] = f2bf(acc[t][i]);
            }
        }
    }
}

// ---------------------------------------------------------------------------
// build_csr_both: 3 block ranges.
//   [0,NB):       dst-direction CSR from bins
//   [NB,2NB):     src-direction CSR + ulist (node sweep)
//   [2NB,2NB+SCB): h1b *= rsqrt(max(cnt_src,1))  -- pre-scales norm_src into
//                 h1 so agg1's inner loop drops its per-edge nrm gather.
__global__ __launch_bounds__(256) void build_csr_both(
    const unsigned* __restrict__ bkt_d, const int* __restrict__ cur_d,
    const unsigned* __restrict__ bkt_s, const int* __restrict__ cur_s,
    const void* __restrict__ mask, const int* __restrict__ flag,
    const int* __restrict__ cnt_src,
    int* __restrict__ adj_dst, int* __restrict__ cnt_dst,
    int* __restrict__ adj_s, int* __restrict__ cnt_u, int* __restrict__ cnt_m,
    int* __restrict__ n_un, int* __restrict__ ulist,
    unsigned short* __restrict__ h1b) {
    __shared__ int lu[512], lm[512];
    int bb = blockIdx.x, tid = threadIdx.x;
    lu[tid] = 0; lu[tid + 256] = 0; lm[tid] = 0; lm[tid + 256] = 0;
    __syncthreads();
    if (bb < NB) {
        int b = bb;
        int n = cur_d[b]; if (n > CAPB_D) n = CAPB_D;
        int n0 = b << BSH;
        const unsigned* base = bkt_d + (size_t)b * CAPB_D;
        for (int i = tid; i < n; i += 256) {
            unsigned r = base[i];
            int d = r >> 16, s = r & 0xffff;
            int sl = atomicAdd(&lu[d - n0], 1);
            if (sl < CAPD) adj_dst[d * CAPD + sl] = s;
        }
        __syncthreads();
        int g0 = n0 + tid;
        if (g0 < Nn) cnt_dst[g0] = lu[tid];
        g0 += 256;
        if (g0 < Nn) cnt_dst[g0] = lu[tid + 256];
    } else if (bb < 2 * NB) {
        int b = bb - NB;
        int fmt = *flag;
        int n = cur_s[b]; if (n > CAPB_S) n = CAPB_S;
        int n0 = b << BSH;
        const unsigned* base = bkt_s + (size_t)b * CAPB_S;
        for (int i = tid; i < n; i += 256) {
            unsigned r = base[i];
            int s = r >> 16, d = r & 0xffff;
            if (read_mask(mask, d, fmt)) {
                int sl = atomicAdd(&lm[s - n0], 1);
                if (sl < CAPS) adj_s[s * CAPS + (CAPS - 1 - sl)] = d;
            } else {
                int sl = atomicAdd(&lu[s - n0], 1);
                if (sl < CAPS) adj_s[s * CAPS + sl] = d;
            }
        }
        __syncthreads();
        int g0 = n0 + tid;
        if (g0 < Nn) {
            cnt_u[g0] = lu[tid]; cnt_m[g0] = lm[tid];
            if (!read_mask(mask, g0, fmt)) {
                int p = atomicAdd(n_un, 1);
                ulist[p] = g0;
            }
        }
        g0 += 256;
        if (g0 < Nn) {
            cnt_u[g0] = lu[tid + 256]; cnt_m[g0] = lm[tid + 256];
            if (!read_mask(mask, g0, fmt)) {
                int p = atomicAdd(n_un, 1);
                ulist[p] = g0;
            }
        }
    } else {
        // ---- h1b scale range: 256 rows/block, 8 threads/row ----
        int b = bb - 2 * NB;
        int rbase = b * 256;
        int c8 = tid & 7;
#pragma unroll 1
        for (int it = 0; it < 8; it++) {
            int r = rbase + it * 32 + (tid >> 3);
            if (r >= Nn) continue;
            int cs = cnt_src[r];
            float nr = rsqrtf((float)(cs > 1 ? cs : 1));
            uint4* row = (uint4*)(h1b + (size_t)r * HID);
#pragma unroll
            for (int h = 0; h < 2; h++) {
                uint4 u = row[c8 * 2 + h];
                u.x = f2bf2(bf_lo(u.x) * nr, bf_hi(u.x) * nr);
                u.y = f2bf2(bf_lo(u.y) * nr, bf_hi(u.y) * nr);
                u.z = f2bf2(bf_lo(u.z) * nr, bf_hi(u.z) * nr);
                u.w = f2bf2(bf_lo(u.w) * nr, bf_hi(u.w) * nr);
                row[c8 * 2 + h] = u;
            }
        }
    }
}

// ---------------------------------------------------------------------------
// Device bodies (identical numerics to r9 passing kernels).

// agg1 (bf16 out): x1b[node] = relu(norm_dst * sum h1b[src] + b1), h1b
// pre-scaled by norm_src in build_csr_both. Zero LDS (latency-bound gather).
__device__ inline void do_agg1b(
    int node, int l, const uint4* __restrict__ h1b,
    const int* __restrict__ adj_dst, const int* __restrict__ cnt_dst,
    const float4* __restrict__ b1, uint4* __restrict__ x1b) {
    int dg = cnt_dst[node];
    int cnt = dg < CAPD ? dg : CAPD;
    const int* lst = adj_dst + (size_t)node * CAPD;
    float s0 = 0.f, s1 = 0.f, s2 = 0.f, s3 = 0.f;
    float s4 = 0.f, s5 = 0.f, s6 = 0.f, s7 = 0.f;
    int e = 0;
    for (; e + 8 <= cnt; e += 8) {
        uint4 u[8];
#pragma unroll
        for (int q = 0; q < 8; q++) u[q] = h1b[(size_t)lst[e + q] * 16 + l];
#pragma unroll
        for (int q = 0; q < 8; q++) {
            s0 += bf_lo(u[q].x); s1 += bf_hi(u[q].x);
            s2 += bf_lo(u[q].y); s3 += bf_hi(u[q].y);
            s4 += bf_lo(u[q].z); s5 += bf_hi(u[q].z);
            s6 += bf_lo(u[q].w); s7 += bf_hi(u[q].w);
        }
    }
    for (; e < cnt; e++) {
        uint4 u = h1b[(size_t)lst[e] * 16 + l];
        s0 += bf_lo(u.x); s1 += bf_hi(u.x);
        s2 += bf_lo(u.y); s3 += bf_hi(u.y);
        s4 += bf_lo(u.z); s5 += bf_hi(u.z);
        s6 += bf_lo(u.w); s7 += bf_hi(u.w);
    }
    float nrm = rsqrtf((float)(dg > 1 ? dg : 1));
    float4 bb0 = b1[l * 2], bb1 = b1[l * 2 + 1];
    float v0x = fmaxf(s0 * nrm + bb0.x, 0.f);
    float v0y = fmaxf(s1 * nrm + bb0.y, 0.f);
    float v0z = fmaxf(s2 * nrm + bb0.z, 0.f);
    float v0w = fmaxf(s3 * nrm + bb0.w, 0.f);
    float v1x = fmaxf(s4 * nrm + bb1.x, 0.f);
    float v1y = fmaxf(s5 * nrm + bb1.y, 0.f);
    float v1z = fmaxf(s6 * nrm + bb1.z, 0.f);
    float v1w = fmaxf(s7 * nrm + bb1.w, 0.f);
    uint4 pk4;
    pk4.x = f2bf2(v0x, v0y);
    pk4.y = f2bf2(v0z, v0w);
    pk4.z = f2bf2(v1x, v1y);
    pk4.w = f2bf2(v1z, v1w);
    x1b[(size_t)node * 16 + l] = pk4;
}

__device__ inline void do_lpa_const(
    int g, int l, const float4* __restrict__ labels,
    const int* __restrict__ ulist, const int* __restrict__ adj_s,
    const int* __restrict__ cnt_m, float4* __restrict__ sconst,
    uint2* __restrict__ y1b) {
    int u = ulist[g];
    int cm = cnt_m[u];
    int cnt = cm < CAPS ? cm : CAPS;
    const int* lst = adj_s + (size_t)u * CAPS + (CAPS - cnt);
    float4 s = make_float4(0.f, 0.f, 0.f, 0.f);
    int e = 0;
    for (; e + 8 <= cnt; e += 8) {
        float4 v[8];
#pragma unroll
        for (int q = 0; q < 8; q++) v[q] = labels[(size_t)lst[e + q] * 10 + l];
#pragma unroll
        for (int q = 0; q < 8; q++) {
            s.x += v[q].x; s.y += v[q].y; s.z += v[q].z; s.w += v[q].w;
        }
    }
    for (; e + 4 <= cnt; e += 4) {
        float4 v[4];
#pragma unroll
        for (int q = 0; q < 4; q++) v[q] = labels[(size_t)lst[e + q] * 10 + l];
#pragma unroll
        for (int q = 0; q < 4; q++) {
            s.x += v[q].x; s.y += v[q].y; s.z += v[q].z; s.w += v[q].w;
        }
    }
    for (; e < cnt; e++) {
        float4 a = labels[(size_t)lst[e] * 10 + l];
        s.x += a.x; s.y += a.y; s.z += a.z; s.w += a.w;
    }
    sconst[(size_t)u * 10 + l] = s;
    uint2 pk; pk.x = f2bf2(s.x, s.y); pk.y = f2bf2(s.z, s.w);
    y1b[(size_t)u * 10 + l] = pk;
}

__device__ inline void do_lpa_mid(
    int g, int l, const uint2* __restrict__ ycur,
    const int* __restrict__ ulist, const int* __restrict__ adj_s,
    const int* __restrict__ cnt_u, const float4* __restrict__ sconst,
    uint2* __restrict__ ynext) {
    int u = ulist[g];
    int cu = cnt_u[u];
    int cnt = cu < CAPS ? cu : CAPS;
    const int* lst = adj_s + (size_t)u * CAPS;
    float4 s = sconst[(size_t)u * 10 + l];
    int e = 0;
    for (; e + 8 <= cnt; e += 8) {
        uint2 v[8];
#pragma unroll
        for (int q = 0; q < 8; q++) v[q] = ycur[(size_t)lst[e + q] * 10 + l];
#pragma unroll
        for (int q = 0; q < 8; q++) {
            s.x += bf_lo(v[q].x); s.y += bf_hi(v[q].x);
            s.z += bf_lo(v[q].y); s.w += bf_hi(v[q].y);
        }
    }
    for (; e + 4 <= cnt; e += 4) {
        uint2 v[4];
#pragma unroll
        for (int q = 0; q < 4; q++) v[q] = ycur[(size_t)lst[e + q] * 10 + l];
#pragma unroll
        for (int q = 0; q < 4; q++) {
            s.x += bf_lo(v[q].x); s.y += bf_hi(v[q].x);
            s.z += bf_lo(v[q].y); s.w += bf_hi(v[q].y);
        }
    }
    for (; e < cnt; e++) {
        uint2 v = ycur[(size_t)lst[e] * 10 + l];
        s.x += bf_lo(v.x); s.y += bf_hi(v.x);
        s.z += bf_lo(v.y); s.w += bf_hi(v.y);
    }
    uint2 pk; pk.x = f2bf2(s.x, s.y); pk.y = f2bf2(s.z, s.w);
    ynext[(size_t)u * 10 + l] = pk;
}

__device__ inline void do_agg2(
    int node, int l, const uint2* __restrict__ h2b,
    const int* __restrict__ adj_dst, const int* __restrict__ cnt_dst,
    const float4* __restrict__ b2, float4* __restrict__ out_x) {
    int dg = cnt_dst[node];
    int cnt = dg < CAPD ? dg : CAPD;
    const int* lst = adj_dst + (size_t)node * CAPD;
    float s0 = 0.f, s1 = 0.f, s2 = 0.f, s3 = 0.f;
    int e = 0;
    for (; e + 8 <= cnt; e += 8) {
        uint2 u[8];
#pragma unroll
        for (int q = 0; q < 8; q++) u[q] = h2b[(size_t)lst[e + q] * 10 + l];
#pragma unroll
        for (int q = 0; q < 8; q++) {
            s0 += bf_lo(u[q].x); s1 += bf_hi(u[q].x);
            s2 += bf_lo(u[q].y); s3 += bf_hi(u[q].y);
        }
    }
    for (; e + 4 <= cnt; e += 4) {
        uint2 u[4];
#pragma unroll
        for (int q = 0; q < 4; q++) u[q] = h2b[(size_t)lst[e + q] * 10 + l];
#pragma unroll
        for (int q = 0; q < 4; q++) {
            s0 += bf_lo(u[q].x); s1 += bf_hi(u[q].x);
            s2 += bf_lo(u[q].y); s3 += bf_hi(u[q].y);
        }
    }
    for (; e < cnt; e++) {
        uint2 u = h2b[(size_t)lst[e] * 10 + l];
        s0 += bf_lo(u.x); s1 += bf_hi(u.x);
        s2 += bf_lo(u.y); s3 += bf_hi(u.y);
    }
    float nrm = rsqrtf((float)(dg > 1 ? dg : 1));
    float4 bb = b2[l];
    float4 v;
    v.x = s0 * nrm + bb.x;
    v.y = s1 * nrm + bb.y;
    v.z = s2 * nrm + bb.z;
    v.w = s3 * nrm + bb.w;
    out_x[(size_t)node * 10 + l] = v;
}

// ---------------------------------------------------------------------------
// Pipeline-sliced fused kernels: each GCN slice carries one LPA iteration.
// Splitting per-node kernels into sequential slices costs ~nothing (same
// total gathers) while hiding formerly-standalone lpa_mid dispatches.

// K1 = agg1 slice ∥ lpa_const + masked out_y copy (iter 1)
__global__ __launch_bounds__(320) void k_agg1_lconst(
    const int node0, const int nagg,
    const uint4* __restrict__ h1b, const int* __restrict__ adj_dst,
    const int* __restrict__ cnt_dst, const float4* __restrict__ b1,
    uint4* __restrict__ x1b,
    const float4* __restrict__ labels, const void* __restrict__ mask,
    const int* __restrict__ flag, const int* __restrict__ n_un,
    const int* __restrict__ ulist, const int* __restrict__ adj_s,
    const int* __restrict__ cnt_m, float4* __restrict__ sconst,
    uint2* __restrict__ y1b, float4* __restrict__ out_y4) {
    int bb = blockIdx.x, tid = threadIdx.x;
    if (bb < nagg) {
        do_agg1b(node0 + bb * 20 + (tid >> 4), tid & 15,
                 h1b, adj_dst, cnt_dst, b1, x1b);
    } else {
        int lb = bb - nagg;
        int fmt = *flag;
        int i = lb * 320 + tid;
        if (i < Nn * 10) {                 // NC/4 = 10 float4 per node
            int node = i / 10;
            if (read_mask(mask, node, fmt)) out_y4[i] = labels[i];
        }
        int g = lb * 32 + tid / 10;
        if (g < *n_un)
            do_lpa_const(g, tid % 10, labels, ulist, adj_s, cnt_m, sconst, y1b);
    }
}

// K2/K3 = agg1 slice ∥ lpa_mid
__global__ __launch_bounds__(320) void k_agg1_mid(
    const int node0, const int nagg,
    const uint4* __restrict__ h1b, const int* __restrict__ adj_dst,
    const int* __restrict__ cnt_dst, const float4* __restrict__ b1,
    uint4* __restrict__ x1b,
    const uint2* __restrict__ ycur, const int* __restrict__ n_un,
    const int* __restrict__ ulist, const int* __restrict__ adj_s,
    const int* __restrict__ cnt_u, const float4* __restrict__ sconst,
    uint2* __restrict__ ynext) {
    int bb = blockIdx.x, tid = threadIdx.x;
    if (bb < nagg) {
        do_agg1b(node0 + bb * 20 + (tid >> 4), tid & 15,
                 h1b, adj_dst, cnt_dst, b1, x1b);
    } else {
        int g = (bb - nagg) * 32 + tid / 10;
        if (g < *n_un)
            do_lpa_mid(g, tid % 10, ycur, ulist, adj_s, cnt_u, sconst, ynext);
    }
}

// K4/K5 = gemm2 slice (W2 20KB LDS, one thread = one node row, bf16 x1 in)
//         ∥ lpa_mid
__global__ __launch_bounds__(320) void k_gemm2_mid(
    const int row0, const int ngem,
    const uint4* __restrict__ x1b, const float4* __restrict__ W2,
    const int* __restrict__ cnt_src, unsigned* __restrict__ h2b,
    const uint2* __restrict__ ycur, const int* __restrict__ n_un,
    const int* __restrict__ ulist, const int* __restrict__ adj_s,
    const int* __restrict__ cnt_u, const float4* __restrict__ sconst,
    uint2* __restrict__ ynext) {
    __shared__ float lw[HID * NC];   // 20KB (gemm half only)
    int bb = blockIdx.x, tid = threadIdx.x;
    if (bb < ngem) {
        for (int i = tid; i < HID * NC / 4; i += 320)
            ((float4*)lw)[i] = W2[i];
        __syncthreads();
        int r = row0 + bb * 320 + tid;
        if (r >= Nn) return;
        const uint4* xr = x1b + (size_t)r * 16;
        float4 acc[10];
#pragma unroll
        for (int j = 0; j < 10; j++) acc[j] = make_float4(0.f, 0.f, 0.f, 0.f);
        for (int kk = 0; kk < 16; kk++) {
            uint4 u = xr[kk];
            float xv[8];
            xv[0] = bf_lo(u.x); xv[1] = bf_hi(u.x);
            xv[2] = bf_lo(u.y); xv[3] = bf_hi(u.y);
            xv[4] = bf_lo(u.z); xv[5] = bf_hi(u.z);
            xv[6] = bf_lo(u.w); xv[7] = bf_hi(u.w);
#pragma unroll
            for (int s = 0; s < 8; s++) {
                float x = xv[s];
                const float4* wrow = (const float4*)(lw + (kk * 8 + s) * NC);
#pragma unroll
                for (int j = 0; j < 10; j++) {
                    float4 w = wrow[j];
                    acc[j].x += x * w.x; acc[j].y += x * w.y;
                    acc[j].z += x * w.z; acc[j].w += x * w.w;
                }
            }
        }
        int dg = cnt_src[r];
        float nrm = rsqrtf((float)(dg > 1 ? dg : 1));
        uint2* out = (uint2*)(h2b + (size_t)r * 20);
#pragma unroll
        for (int j = 0; j < 10; j++) {
            uint2 pk;
            pk.x = f2bf2(acc[j].x * nrm, acc[j].y * nrm);
            pk.y = f2bf2(acc[j].z * nrm, acc[j].w * nrm);
            out[j] = pk;
        }
    } else {
        int g = (bb - ngem) * 32 + tid / 10;
        if (g < *n_un)
            do_lpa_mid(g, tid % 10, ycur, ulist, adj_s, cnt_u, sconst, ynext);
    }
}

// K6/K7 = agg2 slice ∥ lpa_mid
__global__ __launch_bounds__(320) void k_agg2_mid(
    const int node0, const int nagg,
    const uint2* __restrict__ h2b, const int* __restrict__ adj_dst,
    const int* __restrict__ cnt_dst, const float4* __restrict__ b2,
    float4* __restrict__ out_x,
    const uint2* __restrict__ ycur, const int* __restrict__ n_un,
    const int* __restrict__ ulist, const int* __restrict__ adj_s,
    const int* __restrict__ cnt_u, const float4* __restrict__ sconst,
    uint2* __restrict__ ynext) {
    int bb = blockIdx.x, tid = threadIdx.x;
    if (bb < nagg) {
        int node = node0 + bb * 32 + tid / 10;
        if (node < Nn)
            do_agg2(node, tid % 10, h2b, adj_dst, cnt_dst, b2, out_x);
    } else {
        int g = (bb - nagg) * 32 + tid / 10;
        if (g < *n_un)
            do_lpa_mid(g, tid % 10, ycur, ulist, adj_s, cnt_u, sconst, ynext);
    }
}

__global__ __launch_bounds__(320) void lpa_mid(
    const uint2* __restrict__ ycur, const int* __restrict__ n_un,
    const int* __restrict__ ulist, const int* __restrict__ adj_s,
    const int* __restrict__ cnt_u, const float4* __restrict__ sconst,
    uint2* __restrict__ ynext) {
    int g = blockIdx.x * 32 + threadIdx.x / 10;
    if (g < *n_un)
        do_lpa_mid(g, threadIdx.x % 10, ycur, ulist, adj_s, cnt_u, sconst, ynext);
}

__global__ __launch_bounds__(320) void lpa_last(
    const uint2* __restrict__ ycur, const int* __restrict__ n_un,
    const int* __restrict__ ulist, const int* __restrict__ adj_s,
    const int* __restrict__ cnt_u, const float4* __restrict__ sconst,
    float4* __restrict__ out_y) {
    int g = blockIdx.x * 32 + threadIdx.x / 10;
    int l = threadIdx.x % 10;
    if (g >= *n_un) return;
    int u = ulist[g];
    int cu = cnt_u[u];
    int cnt = cu < CAPS ? cu : CAPS;
    const int* lst = adj_s + (size_t)u * CAPS;
    float4 s = sconst[(size_t)u * 10 + l];
    int e = 0;
    for (; e + 8 <= cnt; e += 8) {
        uint2 v[8];
#pragma unroll
        for (int q = 0; q < 8; q++) v[q] = ycur[(size_t)lst[e + q] * 10 + l];
#pragma unroll
        for (int q = 0; q < 8; q++) {
            s.x += bf_lo(v[q].x); s.y += bf_hi(v[q].x);
            s.z += bf_lo(v[q].y); s.w += bf_hi(v[q].y);
        }
    }
    for (; e + 4 <= cnt; e += 4) {
        uint2 v[4];
#pragma unroll
        for (int q = 0; q < 4; q++) v[q] = ycur[(size_t)lst[e + q] * 10 + l];
#pragma unroll
        for (int q = 0; q < 4; q++) {
            s.x += bf_lo(v[q].x); s.y += bf_hi(v[q].x);
            s.z += bf_lo(v[q].y); s.w += bf_hi(v[q].y);
        }
    }
    for (; e < cnt; e++) {
        uint2 v = ycur[(size_t)lst[e] * 10 + l];
        s.x += bf_lo(v.x); s.y += bf_hi(v.x);
        s.z += bf_lo(v.y); s.w += bf_hi(v.y);
    }
    out_y[(size_t)u * 10 + l] = s;
}

// ---------------------------------------------------------------------------
extern "C" void kernel_launch(void* const* d_in, const int* in_sizes, int n_in,
                              void* d_out, int out_size, void* d_ws, size_t ws_size,
                              hipStream_t stream) {
    const float* feat   = (const float*)d_in[0];
    const float* labels = (const float*)d_in[1];
    const void*  mask   = d_in[2];
    const int*   src    = (const int*)d_in[3];
    const int*   dst    = (const int*)d_in[4];
    const float* W1     = (const float*)d_in[5];
    const float* b1     = (const float*)d_in[6];
    const float* W2     = (const float*)d_in[7];
    const float* b2     = (const float*)d_in[8];

    float* out_x = (float*)d_out;
    float* out_y = out_x + (size_t)Nn * NC;

    char* ws = (char*)d_ws;
    size_t off = 0;
    auto alloc = [&](size_t bytes) -> void* {
        void* p = ws + off;
        off += (bytes + 255) & ~(size_t)255;
        return p;
    };
    // --- zeroed header ---
    int* flag    = (int*)alloc(256);   // flag[0]=fmt, flag[1]=n_un
    int* n_un    = flag + 1;
    int* cnt_src = (int*)alloc((size_t)Nn * 4);
    int* cur_d   = (int*)alloc(512);
    int* cur_s   = (int*)alloc(512);
    size_t zero_bytes = off;
    // --- non-zeroed ---
    int* cnt_dst = (int*)alloc((size_t)Nn * 4);
    int* cnt_u   = (int*)alloc((size_t)Nn * 4);
    int* cnt_m   = (int*)alloc((size_t)Nn * 4);
    int* ulist   = (int*)alloc((size_t)Nn * 4);
    unsigned short* W1t = (unsigned short*)alloc((size_t)HID * INF_ * 2); // 64KB
    // bins live concurrently with h1b (phase1 overlap) -> no aliasing
    unsigned* bkt_d = (unsigned*)alloc((size_t)NB * CAPB_D * 4);  // ~4.0MB
    unsigned* bkt_s = (unsigned*)alloc((size_t)NB * CAPB_S * 4);  // ~2.4MB
    unsigned short* h1b = (unsigned short*)alloc((size_t)Nn * HID * 2); // 12.8MB
    uint4* x1b = (uint4*)alloc((size_t)Nn * HID * 2);       // bf16 x1, 12.8MB
    int* adj_s   = (int*)alloc((size_t)Nn * CAPS * 4);
    int* adj_dst = (int*)alloc((size_t)Nn * CAPD * 4);
    unsigned* h2b = (unsigned*)alloc((size_t)Nn * NC * 2);  // bf16 h2
    float* sconst = (float*)alloc((size_t)Nn * NC * 4);
    uint2* y1b = (uint2*)alloc((size_t)Nn * NC * 2);        // bf16 y ping
    uint2* y2b = (uint2*)alloc((size_t)Nn * NC * 2);        // bf16 y pong

    hipMemsetAsync(d_ws, 0, zero_bytes, stream);

    detect_prep<<<49 + HID, 256, 0, stream>>>((const unsigned int*)mask, flag,
                                              W1, W1t);
    phase1<<<NBLK + G1BLK, 256, 0, stream>>>(
        src, dst, mask, flag, cnt_src, cur_d, cur_s, bkt_d, bkt_s,
        feat, W1t, h1b);
    build_csr_both<<<NB * 2 + SCB, 256, 0, stream>>>(
        bkt_d, cur_d, bkt_s, cur_s, mask, flag, cnt_src,
        adj_dst, cnt_dst, adj_s, cnt_u, cnt_m, n_un, ulist, h1b);

    // --- GCN pipeline slices, each carrying one LPA iteration (1..7) ---
    k_agg1_lconst<<<A1T1 + LPA_BLKS, 320, 0, stream>>>(           // iter 1
        0, A1T1, (const uint4*)h1b, adj_dst, cnt_dst, (const float4*)b1, x1b,
        (const float4*)labels, mask, flag, n_un, ulist, adj_s,
        cnt_m, (float4*)sconst, y1b, (float4*)out_y);
    k_agg1_mid<<<A1T2 + LPA_BLKS, 320, 0, stream>>>(              // iter 2
        16680, A1T2, (const uint4*)h1b, adj_dst, cnt_dst, (const float4*)b1,
        x1b, y1b, n_un, ulist, adj_s, cnt_u, (const float4*)sconst, y2b);
    k_agg1_mid<<<A1T3 + LPA_BLKS, 320, 0, stream>>>(              // iter 3
        33340, A1T3, (const uint4*)h1b, adj_dst, cnt_dst, (const float4*)b1,
        x1b, y2b, n_un, ulist, adj_s, cnt_u, (const float4*)sconst, y1b);
    k_gemm2_mid<<<G2H1 + LPA_BLKS, 320, 0, stream>>>(             // iter 4
        0, G2H1, (const uint4*)x1b, (const float4*)W2, cnt_src, h2b,
        y1b, n_un, ulist, adj_s, cnt_u, (const float4*)sconst, y2b);
    k_gemm2_mid<<<G2H2 + LPA_BLKS, 320, 0, stream>>>(             // iter 5
        25280, G2H2, (const uint4*)x1b, (const float4*)W2, cnt_src, h2b,
        y2b, n_un, ulist, adj_s, cnt_u, (const float4*)sconst, y1b);
    k_agg2_mid<<<AG2H1 + LPA_BLKS, 320, 0, stream>>>(             // iter 6
        0, AG2H1, (const uint2*)h2b, adj_dst, cnt_dst, (const float4*)b2,
        (float4*)out_x, y1b, n_un, ulist, adj_s, cnt_u,
        (const float4*)sconst, y2b);
    k_agg2_mid<<<AG2H2 + LPA_BLKS, 320, 0, stream>>>(             // iter 7
        25024, AG2H2, (const uint2*)h2b, adj_dst, cnt_dst, (const float4*)b2,
        (float4*)out_x, y2b, n_un, ulist, adj_s, cnt_u,
        (const float4*)sconst, y1b);

    // --- LPA iterations 8, 9 standalone, then 10 ---
    lpa_mid<<<LPA_BLKS, 320, 0, stream>>>(                        // iter 8
        y1b, n_un, ulist, adj_s, cnt_u, (const float4*)sconst, y2b);
    lpa_mid<<<LPA_BLKS, 320, 0, stream>>>(                        // iter 9
        y2b, n_un, ulist, adj_s, cnt_u, (const float4*)sconst, y1b);
    lpa_last<<<LPA_BLKS, 320, 0, stream>>>(                       // iter 10
        y1b, n_un, ulist, adj_s, cnt_u, (const float4*)sconst, (float4*)out_y);
}

// Round 11
// 360.957 us; speedup vs baseline: 1.0990x; 1.0990x over previous
//
#include <hip/hip_runtime.h>

#define Nn 50000
#define Ee 800000
#define INF_ 256
#define HID 128
#define NC 40
#define CAPD 48      // adj_dst row capacity (Poisson(16) tail @48 ~1e-11)
#define CAPS 48      // adj_s row capacity (u-list front, m-list back)
#define LPA_ITERS 10
#define NB 98        // node buckets of 512
#define BSH 9
#define EPB 1024     // edges per bin block
#define NBLK ((Ee + EPB - 1) / EPB)   // 782
#define G1_ROWS 64
#define G1BLK ((Nn + G1_ROWS - 1) / G1_ROWS)  // 782
#define CAPB_D 10240 // per-bucket bin capacity, dst direction (mean 8163)
#define CAPB_S 6144  // per-bucket bin capacity, src/unmasked (mean ~4081)
#define AGG1_BLKS 2500        // 20 nodes/block @ 320 threads
#define LPA_BLKS ((Nn + 31) / 32)   // 1563
#define GEMM2_BLKS ((Nn + 319) / 320) // 157
#define SCB 196               // h1b-scale blocks (256 rows each)

typedef __attribute__((ext_vector_type(8))) short bfrag;
typedef __attribute__((ext_vector_type(4))) float ffrag;

// ---- bf16 helpers (fp32 math, bf16 storage; RNE rounding) ------------------
__device__ inline unsigned f2bf2(float a, float b) {
    unsigned ua = __float_as_uint(a); ua += 0x7FFFu + ((ua >> 16) & 1u);
    unsigned ub = __float_as_uint(b); ub += 0x7FFFu + ((ub >> 16) & 1u);
    return (ua >> 16) | (ub & 0xFFFF0000u);
}
__device__ inline unsigned short f2bf(float a) {
    unsigned ua = __float_as_uint(a); ua += 0x7FFFu + ((ua >> 16) & 1u);
    return (unsigned short)(ua >> 16);
}
__device__ inline float bf_lo(unsigned u) { return __uint_as_float(u << 16); }
__device__ inline float bf_hi(unsigned u) { return __uint_as_float(u & 0xFFFF0000u); }

__device__ inline bool read_mask(const void* mask, int node, int fmt) {
    if (fmt) return ((const unsigned char*)mask)[node] != 0;
    return ((const int*)mask)[node] != 0;
}

// ---------------------------------------------------------------------------
// detect_prep: mask-format probe (in_sizes is element-count based; device
// probe is load-bearing) + W1 transpose, block-range fused.
__global__ __launch_bounds__(256) void detect_prep(
    const unsigned int* __restrict__ m, int* flag,
    const float* __restrict__ W1, unsigned short* __restrict__ W1t) {
    int bb = blockIdx.x, tid = threadIdx.x;
    if (bb < 49) {
        int i = bb * 256 + tid;
        if (i < 12500) {
            if (m[i] > 1u) atomicOr(flag, 1);
        }
    } else {
        int c = bb - 49;     // 0..127
        W1t[c * INF_ + tid] = f2bf(W1[(size_t)tid * HID + c]);
    }
}

// ---------------------------------------------------------------------------
// phase1: block-range fusion of edge binning + GEMM1 (validated r4: 80us).
__global__ __launch_bounds__(256) void phase1(
    const int* __restrict__ src, const int* __restrict__ dst,
    const void* __restrict__ mask, const int* __restrict__ flag,
    int* __restrict__ cnt_src, int* __restrict__ cur_d, int* __restrict__ cur_s,
    unsigned* __restrict__ bkt_d, unsigned* __restrict__ bkt_s,
    const float* __restrict__ feat, const unsigned short* __restrict__ W1t,
    unsigned short* __restrict__ h1b) {
    __shared__ uint4 smem[784];   // 12544 B, unioned between the two halves
    const int tid = threadIdx.x;
    if (blockIdx.x < NBLK) {
        // ---------------- edge binning half ----------------
        unsigned* stage_d = (unsigned*)smem;          // EPB
        unsigned* stage_s = stage_d + EPB;            // EPB
        int* hd  = (int*)(stage_s + EPB);
        int* od  = hd + NB;                           // NB+1
        int* cd  = od + NB + 1;
        int* gd_ = cd + NB;
        int* hs  = gd_ + NB;
        int* os_ = hs + NB;                           // NB+1
        int* cs_ = os_ + NB + 1;
        int* gs_ = cs_ + NB;
        int lane = tid & 63;
        int wid = tid >> 6;
        int e0 = blockIdx.x * EPB;
        int fmt = *flag;
        if (tid < NB) { hd[tid] = 0; hs[tid] = 0; }
        __syncthreads();                                     // barrier 1

        int rs[EPB / 256], rd[EPB / 256];
        unsigned um = 0;  // bit k: src unmasked
#pragma unroll
        for (int k = 0; k < EPB / 256; k++) {
            int e = e0 + tid + k * 256;
            rs[k] = -1; rd[k] = -1;
            if (e < Ee) {
                int s = src[e], d = dst[e];
                rs[k] = s; rd[k] = d;
                atomicAdd(&cnt_src[s], 1);                   // fire-and-forget
                atomicAdd(&hd[d >> BSH], 1);
                if (!read_mask(mask, s, fmt)) {
                    um |= (1u << k);
                    atomicAdd(&hs[s >> BSH], 1);
                }
            }
        }
        __syncthreads();                                     // barrier 2
        // single-wave exclusive scans: wave 0 -> od, wave 1 -> os_
        if (wid < 2) {
            int* h = wid ? hs : hd;
            int* o = wid ? os_ : od;
            int i0 = lane * 2;
            int v0 = (i0 < NB) ? h[i0] : 0;
            int v1 = (i0 + 1 < NB) ? h[i0 + 1] : 0;
            int s = v0 + v1;
#pragma unroll
            for (int d = 1; d < 64; d <<= 1) {
                int t = __shfl_up(s, d);
                if (lane >= d) s += t;
            }
            int excl = s - v0 - v1;
            if (i0 < NB) o[i0] = excl;
            if (i0 + 1 < NB) o[i0 + 1] = excl + v0;
            if (lane == 63) o[NB] = s;
        }
        __syncthreads();                                     // barrier 3
        if (tid < NB) {
            gd_[tid] = hd[tid] ? atomicAdd(&cur_d[tid], hd[tid]) : 0;
            gs_[tid] = hs[tid] ? atomicAdd(&cur_s[tid], hs[tid]) : 0;
            cd[tid] = od[tid];
            cs_[tid] = os_[tid];
        }
        __syncthreads();                                     // barrier 4
#pragma unroll
        for (int k = 0; k < EPB / 256; k++) {
            if (rd[k] >= 0) {
                int p = atomicAdd(&cd[rd[k] >> BSH], 1);
                stage_d[p] = ((unsigned)rd[k] << 16) | (unsigned)rs[k];
                if (um & (1u << k)) {
                    int q = atomicAdd(&cs_[rs[k] >> BSH], 1);
                    stage_s[q] = ((unsigned)rs[k] << 16) | (unsigned)rd[k];
                }
            }
        }
        __syncthreads();                                     // barrier 5
        // per-bucket writeback: wave w handles buckets w, w+4, ...
        for (int b = wid; b < NB; b += 4) {
            int base = od[b], cntb = hd[b], g0 = gd_[b];
            unsigned* gb = bkt_d + (size_t)b * CAPB_D;
            for (int i = lane; i < cntb; i += 64) {
                int pos = g0 + i;
                if (pos < CAPB_D) gb[pos] = stage_d[base + i];
            }
            int bs = os_[b], cnts = hs[b], gs0 = gs_[b];
            unsigned* gbs = bkt_s + (size_t)b * CAPB_S;
            for (int i = lane; i < cnts; i += 64) {
                int pos = gs0 + i;
                if (pos < CAPB_S) gbs[pos] = stage_s[bs + i];
            }
        }
    } else {
        // ---------------- GEMM1 half (no norm) ----------------
        unsigned short* lA = (unsigned short*)smem;   // [row][k] bf16, 4KB
        unsigned short* lB = lA + G1_ROWS * 32;       // [col][k] bf16, 8KB
        const int row0 = (blockIdx.x - NBLK) * G1_ROWS;
        const int w = tid >> 6;
        const int l = tid & 63;
        const int lane15 = l & 15;
        const int quad = l >> 4;
        const int rw0 = w * 16;

        ffrag acc[8];
#pragma unroll
        for (int t = 0; t < 8; t++) acc[t] = (ffrag){0.f, 0.f, 0.f, 0.f};

        for (int k0 = 0; k0 < INF_; k0 += 32) {
#pragma unroll
            for (int p = 0; p < 2; p++) {
                int idx = tid + p * 256;
                int r = idx >> 3, c4 = idx & 7;
                int grow = row0 + r;
                float4 v = make_float4(0.f, 0.f, 0.f, 0.f);
                if (grow < Nn)
                    v = *(const float4*)(feat + (size_t)grow * INF_ + k0 + c4 * 4);
                uint2 pk;
                pk.x = f2bf2(v.x, v.y);
                pk.y = f2bf2(v.z, v.w);
                *(uint2*)((char*)lA + r * 64 + c4 * 8) = pk;
            }
#pragma unroll
            for (int p = 0; p < 2; p++) {
                int idx = tid + p * 256;
                int col = idx >> 2, q = idx & 3;
                uint4 v = *(const uint4*)((const char*)W1t + col * 512 + k0 * 2 + q * 16);
                *(uint4*)((char*)lB + col * 64 + q * 16) = v;
            }
            __syncthreads();
            int arow = rw0 + lane15;
            bfrag af = *(const bfrag*)((const char*)lA + arow * 64 + quad * 16);
#pragma unroll
            for (int t = 0; t < 8; t++) {
                int col = t * 16 + lane15;
                bfrag bf = *(const bfrag*)((const char*)lB + col * 64 + quad * 16);
                acc[t] = __builtin_amdgcn_mfma_f32_16x16x32_bf16(af, bf, acc[t], 0, 0, 0);
            }
            __syncthreads();
        }
#pragma unroll
        for (int t = 0; t < 8; t++) {
#pragma unroll
            for (int i = 0; i < 4; i++) {
                int grow = row0 + rw0 + quad * 4 + i;
                if (grow < Nn)
                    h1b[(size_t)grow * HID + t * 16 + lane15] = f2bf(acc[t][i]);
            }
        }
    }
}

// ---------------------------------------------------------------------------
// build_csr_both: 3 block ranges.
//   [0,NB):       dst-direction CSR from bins
//   [NB,2NB):     src-direction CSR + ulist (node sweep)
//   [2NB,2NB+SCB): h1b *= rsqrt(max(cnt_src,1))  -- pre-scales norm_src into
//                 h1 so agg1's inner loop drops its per-edge nrm gather.
__global__ __launch_bounds__(256) void build_csr_both(
    const unsigned* __restrict__ bkt_d, const int* __restrict__ cur_d,
    const unsigned* __restrict__ bkt_s, const int* __restrict__ cur_s,
    const void* __restrict__ mask, const int* __restrict__ flag,
    const int* __restrict__ cnt_src,
    int* __restrict__ adj_dst, int* __restrict__ cnt_dst,
    int* __restrict__ adj_s, int* __restrict__ cnt_u, int* __restrict__ cnt_m,
    int* __restrict__ n_un, int* __restrict__ ulist,
    unsigned short* __restrict__ h1b) {
    __shared__ int lu[512], lm[512];
    int bb = blockIdx.x, tid = threadIdx.x;
    lu[tid] = 0; lu[tid + 256] = 0; lm[tid] = 0; lm[tid + 256] = 0;
    __syncthreads();
    if (bb < NB) {
        int b = bb;
        int n = cur_d[b]; if (n > CAPB_D) n = CAPB_D;
        int n0 = b << BSH;
        const unsigned* base = bkt_d + (size_t)b * CAPB_D;
        for (int i = tid; i < n; i += 256) {
            unsigned r = base[i];
            int d = r >> 16, s = r & 0xffff;
            int sl = atomicAdd(&lu[d - n0], 1);
            if (sl < CAPD) adj_dst[d * CAPD + sl] = s;
        }
        __syncthreads();
        int g0 = n0 + tid;
        if (g0 < Nn) cnt_dst[g0] = lu[tid];
        g0 += 256;
        if (g0 < Nn) cnt_dst[g0] = lu[tid + 256];
    } else if (bb < 2 * NB) {
        int b = bb - NB;
        int fmt = *flag;
        int n = cur_s[b]; if (n > CAPB_S) n = CAPB_S;
        int n0 = b << BSH;
        const unsigned* base = bkt_s + (size_t)b * CAPB_S;
        for (int i = tid; i < n; i += 256) {
            unsigned r = base[i];
            int s = r >> 16, d = r & 0xffff;
            if (read_mask(mask, d, fmt)) {
                int sl = atomicAdd(&lm[s - n0], 1);
                if (sl < CAPS) adj_s[s * CAPS + (CAPS - 1 - sl)] = d;
            } else {
                int sl = atomicAdd(&lu[s - n0], 1);
                if (sl < CAPS) adj_s[s * CAPS + sl] = d;
            }
        }
        __syncthreads();
        int g0 = n0 + tid;
        if (g0 < Nn) {
            cnt_u[g0] = lu[tid]; cnt_m[g0] = lm[tid];
            if (!read_mask(mask, g0, fmt)) {
                int p = atomicAdd(n_un, 1);
                ulist[p] = g0;
            }
        }
        g0 += 256;
        if (g0 < Nn) {
            cnt_u[g0] = lu[tid + 256]; cnt_m[g0] = lm[tid + 256];
            if (!read_mask(mask, g0, fmt)) {
                int p = atomicAdd(n_un, 1);
                ulist[p] = g0;
            }
        }
    } else {
        // ---- h1b scale range: 256 rows/block, 8 threads/row ----
        int b = bb - 2 * NB;
        int rbase = b * 256;
        int c8 = tid & 7;
#pragma unroll 1
        for (int it = 0; it < 8; it++) {
            int r = rbase + it * 32 + (tid >> 3);
            if (r >= Nn) continue;
            int cs = cnt_src[r];
            float nr = rsqrtf((float)(cs > 1 ? cs : 1));
            uint4* row = (uint4*)(h1b + (size_t)r * HID);
#pragma unroll
            for (int h = 0; h < 2; h++) {
                uint4 u = row[c8 * 2 + h];
                u.x = f2bf2(bf_lo(u.x) * nr, bf_hi(u.x) * nr);
                u.y = f2bf2(bf_lo(u.y) * nr, bf_hi(u.y) * nr);
                u.z = f2bf2(bf_lo(u.z) * nr, bf_hi(u.z) * nr);
                u.w = f2bf2(bf_lo(u.w) * nr, bf_hi(u.w) * nr);
                row[c8 * 2 + h] = u;
            }
        }
    }
}

// ---------------------------------------------------------------------------
// LPA device bodies (identical numerics to r5/r7 passing kernels).

__device__ inline void do_lpa_const(
    int g, int l, const float4* __restrict__ labels,
    const int* __restrict__ ulist, const int* __restrict__ adj_s,
    const int* __restrict__ cnt_m, float4* __restrict__ sconst,
    uint2* __restrict__ y1b) {
    int u = ulist[g];
    int cm = cnt_m[u];
    int cnt = cm < CAPS ? cm : CAPS;
    const int* lst = adj_s + (size_t)u * CAPS + (CAPS - cnt);
    float4 s = make_float4(0.f, 0.f, 0.f, 0.f);
    int e = 0;
    for (; e + 8 <= cnt; e += 8) {
        float4 v[8];
#pragma unroll
        for (int q = 0; q < 8; q++) v[q] = labels[(size_t)lst[e + q] * 10 + l];
#pragma unroll
        for (int q = 0; q < 8; q++) {
            s.x += v[q].x; s.y += v[q].y; s.z += v[q].z; s.w += v[q].w;
        }
    }
    for (; e + 4 <= cnt; e += 4) {
        float4 v[4];
#pragma unroll
        for (int q = 0; q < 4; q++) v[q] = labels[(size_t)lst[e + q] * 10 + l];
#pragma unroll
        for (int q = 0; q < 4; q++) {
            s.x += v[q].x; s.y += v[q].y; s.z += v[q].z; s.w += v[q].w;
        }
    }
    for (; e < cnt; e++) {
        float4 a = labels[(size_t)lst[e] * 10 + l];
        s.x += a.x; s.y += a.y; s.z += a.z; s.w += a.w;
    }
    sconst[(size_t)u * 10 + l] = s;
    uint2 pk; pk.x = f2bf2(s.x, s.y); pk.y = f2bf2(s.z, s.w);
    y1b[(size_t)u * 10 + l] = pk;
}

__device__ inline void do_lpa_mid(
    int g, int l, const uint2* __restrict__ ycur,
    const int* __restrict__ ulist, const int* __restrict__ adj_s,
    const int* __restrict__ cnt_u, const float4* __restrict__ sconst,
    uint2* __restrict__ ynext) {
    int u = ulist[g];
    int cu = cnt_u[u];
    int cnt = cu < CAPS ? cu : CAPS;
    const int* lst = adj_s + (size_t)u * CAPS;
    float4 s = sconst[(size_t)u * 10 + l];
    int e = 0;
    for (; e + 8 <= cnt; e += 8) {
        uint2 v[8];
#pragma unroll
        for (int q = 0; q < 8; q++) v[q] = ycur[(size_t)lst[e + q] * 10 + l];
#pragma unroll
        for (int q = 0; q < 8; q++) {
            s.x += bf_lo(v[q].x); s.y += bf_hi(v[q].x);
            s.z += bf_lo(v[q].y); s.w += bf_hi(v[q].y);
        }
    }
    for (; e + 4 <= cnt; e += 4) {
        uint2 v[4];
#pragma unroll
        for (int q = 0; q < 4; q++) v[q] = ycur[(size_t)lst[e + q] * 10 + l];
#pragma unroll
        for (int q = 0; q < 4; q++) {
            s.x += bf_lo(v[q].x); s.y += bf_hi(v[q].x);
            s.z += bf_lo(v[q].y); s.w += bf_hi(v[q].y);
        }
    }
    for (; e < cnt; e++) {
        uint2 v = ycur[(size_t)lst[e] * 10 + l];
        s.x += bf_lo(v.x); s.y += bf_hi(v.x);
        s.z += bf_lo(v.y); s.w += bf_hi(v.y);
    }
    uint2 pk; pk.x = f2bf2(s.x, s.y); pk.y = f2bf2(s.z, s.w);
    ynext[(size_t)u * 10 + l] = pk;
}

__device__ inline void do_agg2(
    int node, int l, const uint2* __restrict__ h2b,
    const int* __restrict__ adj_dst, const int* __restrict__ cnt_dst,
    const float4* __restrict__ b2, float4* __restrict__ out_x) {
    int dg = cnt_dst[node];
    int cnt = dg < CAPD ? dg : CAPD;
    const int* lst = adj_dst + (size_t)node * CAPD;
    float s0 = 0.f, s1 = 0.f, s2 = 0.f, s3 = 0.f;
    int e = 0;
    for (; e + 8 <= cnt; e += 8) {
        uint2 u[8];
#pragma unroll
        for (int q = 0; q < 8; q++) u[q] = h2b[(size_t)lst[e + q] * 10 + l];
#pragma unroll
        for (int q = 0; q < 8; q++) {
            s0 += bf_lo(u[q].x); s1 += bf_hi(u[q].x);
            s2 += bf_lo(u[q].y); s3 += bf_hi(u[q].y);
        }
    }
    for (; e + 4 <= cnt; e += 4) {
        uint2 u[4];
#pragma unroll
        for (int q = 0; q < 4; q++) u[q] = h2b[(size_t)lst[e + q] * 10 + l];
#pragma unroll
        for (int q = 0; q < 4; q++) {
            s0 += bf_lo(u[q].x); s1 += bf_hi(u[q].x);
            s2 += bf_lo(u[q].y); s3 += bf_hi(u[q].y);
        }
    }
    for (; e < cnt; e++) {
        uint2 u = h2b[(size_t)lst[e] * 10 + l];
        s0 += bf_lo(u.x); s1 += bf_hi(u.x);
        s2 += bf_lo(u.y); s3 += bf_hi(u.y);
    }
    float nrm = rsqrtf((float)(dg > 1 ? dg : 1));
    float4 bb = b2[l];
    float4 v;
    v.x = s0 * nrm + bb.x;
    v.y = s1 * nrm + bb.y;
    v.z = s2 * nrm + bb.z;
    v.w = s3 * nrm + bb.w;
    out_x[(size_t)node * 10 + l] = v;
}

// ---------------------------------------------------------------------------
// K1 = agg_relu1 (ZERO LDS -- the gather is latency-bound and needs waves,
// r7's 31KB-LDS fusion choked it to 22% occupancy) ∥ lpa_const + out_y copy.
// x1 emitted as bf16 (12.8MB; halves gemm2's re-read vs fp32).
__global__ __launch_bounds__(320) void k_agg1_lconst(
    const uint4* __restrict__ h1b, const int* __restrict__ adj_dst,
    const int* __restrict__ cnt_dst, const float4* __restrict__ b1,
    uint4* __restrict__ x1b,
    const float4* __restrict__ labels, const void* __restrict__ mask,
    const int* __restrict__ flag, const int* __restrict__ n_un,
    const int* __restrict__ ulist, const int* __restrict__ adj_s,
    const int* __restrict__ cnt_m, float4* __restrict__ sconst,
    uint2* __restrict__ y1b, float4* __restrict__ out_y4) {
    int bb = blockIdx.x, tid = threadIdx.x;
    if (bb < AGG1_BLKS) {
        const int node = bb * 20 + (tid >> 4);   // 2500*20 = 50000 exact
        const int l = tid & 15;
        int dg = cnt_dst[node];
        int cnt = dg < CAPD ? dg : CAPD;
        const int* lst = adj_dst + (size_t)node * CAPD;
        float s0 = 0.f, s1 = 0.f, s2 = 0.f, s3 = 0.f;
        float s4 = 0.f, s5 = 0.f, s6 = 0.f, s7 = 0.f;
        int e = 0;
        for (; e + 8 <= cnt; e += 8) {
            uint4 u[8];
#pragma unroll
            for (int q = 0; q < 8; q++) u[q] = h1b[(size_t)lst[e + q] * 16 + l];
#pragma unroll
            for (int q = 0; q < 8; q++) {
                s0 += bf_lo(u[q].x); s1 += bf_hi(u[q].x);
                s2 += bf_lo(u[q].y); s3 += bf_hi(u[q].y);
                s4 += bf_lo(u[q].z); s5 += bf_hi(u[q].z);
                s6 += bf_lo(u[q].w); s7 += bf_hi(u[q].w);
            }
        }
        for (; e < cnt; e++) {
            uint4 u = h1b[(size_t)lst[e] * 16 + l];
            s0 += bf_lo(u.x); s1 += bf_hi(u.x);
            s2 += bf_lo(u.y); s3 += bf_hi(u.y);
            s4 += bf_lo(u.z); s5 += bf_hi(u.z);
            s6 += bf_lo(u.w); s7 += bf_hi(u.w);
        }
        float nrm = rsqrtf((float)(dg > 1 ? dg : 1));
        float4 bb0 = b1[l * 2], bb1 = b1[l * 2 + 1];
        float v0x = fmaxf(s0 * nrm + bb0.x, 0.f);
        float v0y = fmaxf(s1 * nrm + bb0.y, 0.f);
        float v0z = fmaxf(s2 * nrm + bb0.z, 0.f);
        float v0w = fmaxf(s3 * nrm + bb0.w, 0.f);
        float v1x = fmaxf(s4 * nrm + bb1.x, 0.f);
        float v1y = fmaxf(s5 * nrm + bb1.y, 0.f);
        float v1z = fmaxf(s6 * nrm + bb1.z, 0.f);
        float v1w = fmaxf(s7 * nrm + bb1.w, 0.f);
        uint4 pk4;
        pk4.x = f2bf2(v0x, v0y);
        pk4.y = f2bf2(v0z, v0w);
        pk4.z = f2bf2(v1x, v1y);
        pk4.w = f2bf2(v1z, v1w);
        x1b[(size_t)node * 16 + l] = pk4;
    } else {
        int lb = bb - AGG1_BLKS;
        int fmt = *flag;
        int i = lb * 320 + tid;
        if (i < Nn * 10) {                 // NC/4 = 10 float4 per node
            int node = i / 10;
            if (read_mask(mask, node, fmt)) out_y4[i] = labels[i];
        }
        int g = lb * 32 + tid / 10;
        if (g < *n_un)
            do_lpa_const(g, tid % 10, labels, ulist, adj_s, cnt_m, sconst, y1b);
    }
}

// K2 = gemm2 (W2 20KB LDS, one thread = one node row, bf16 x1 in) ∥ mid2
__global__ __launch_bounds__(320) void k_gemm2_mid(
    const uint4* __restrict__ x1b, const float4* __restrict__ W2,
    const int* __restrict__ cnt_src, unsigned* __restrict__ h2b,
    const uint2* __restrict__ ycur, const int* __restrict__ n_un,
    const int* __restrict__ ulist, const int* __restrict__ adj_s,
    const int* __restrict__ cnt_u, const float4* __restrict__ sconst,
    uint2* __restrict__ ynext) {
    __shared__ float lw[HID * NC];   // 20KB (gemm half only)
    int bb = blockIdx.x, tid = threadIdx.x;
    if (bb < GEMM2_BLKS) {
        for (int i = tid; i < HID * NC / 4; i += 320)
            ((float4*)lw)[i] = W2[i];
        __syncthreads();
        int r = bb * 320 + tid;
        if (r >= Nn) return;
        const uint4* xr = x1b + (size_t)r * 16;
        float4 acc[10];
#pragma unroll
        for (int j = 0; j < 10; j++) acc[j] = make_float4(0.f, 0.f, 0.f, 0.f);
        for (int kk = 0; kk < 16; kk++) {
            uint4 u = xr[kk];
            float xv[8];
            xv[0] = bf_lo(u.x); xv[1] = bf_hi(u.x);
            xv[2] = bf_lo(u.y); xv[3] = bf_hi(u.y);
            xv[4] = bf_lo(u.z); xv[5] = bf_hi(u.z);
            xv[6] = bf_lo(u.w); xv[7] = bf_hi(u.w);
#pragma unroll
            for (int s = 0; s < 8; s++) {
                float x = xv[s];
                const float4* wrow = (const float4*)(lw + (kk * 8 + s) * NC);
#pragma unroll
                for (int j = 0; j < 10; j++) {
                    float4 w = wrow[j];
                    acc[j].x += x * w.x; acc[j].y += x * w.y;
                    acc[j].z += x * w.z; acc[j].w += x * w.w;
                }
            }
        }
        int dg = cnt_src[r];
        float nrm = rsqrtf((float)(dg > 1 ? dg : 1));
        uint2* out = (uint2*)(h2b + (size_t)r * 20);
#pragma unroll
        for (int j = 0; j < 10; j++) {
            uint2 pk;
            pk.x = f2bf2(acc[j].x * nrm, acc[j].y * nrm);
            pk.y = f2bf2(acc[j].z * nrm, acc[j].w * nrm);
            out[j] = pk;
        }
    } else {
        int g = (bb - GEMM2_BLKS) * 32 + tid / 10;
        if (g < *n_un)
            do_lpa_mid(g, tid % 10, ycur, ulist, adj_s, cnt_u, sconst, ynext);
    }
}

// K3 = agg2 ∥ lpa_mid iter3
__global__ __launch_bounds__(320) void k_agg2_mid(
    const uint2* __restrict__ h2b, const int* __restrict__ adj_dst,
    const int* __restrict__ cnt_dst, const float4* __restrict__ b2,
    float4* __restrict__ out_x,
    const uint2* __restrict__ ycur, const int* __restrict__ n_un,
    const int* __restrict__ ulist, const int* __restrict__ adj_s,
    const int* __restrict__ cnt_u, const float4* __restrict__ sconst,
    uint2* __restrict__ ynext) {
    int bb = blockIdx.x, tid = threadIdx.x;
    if (bb < LPA_BLKS) {
        int node = bb * 32 + tid / 10;
        if (node < Nn)
            do_agg2(node, tid % 10, h2b, adj_dst, cnt_dst, b2, out_x);
    } else {
        int g = (bb - LPA_BLKS) * 32 + tid / 10;
        if (g < *n_un)
            do_lpa_mid(g, tid % 10, ycur, ulist, adj_s, cnt_u, sconst, ynext);
    }
}

__global__ __launch_bounds__(320) void lpa_mid(
    const uint2* __restrict__ ycur, const int* __restrict__ n_un,
    const int* __restrict__ ulist, const int* __restrict__ adj_s,
    const int* __restrict__ cnt_u, const float4* __restrict__ sconst,
    uint2* __restrict__ ynext) {
    int g = blockIdx.x * 32 + threadIdx.x / 10;
    if (g < *n_un)
        do_lpa_mid(g, threadIdx.x % 10, ycur, ulist, adj_s, cnt_u, sconst, ynext);
}

__global__ __launch_bounds__(320) void lpa_last(
    const uint2* __restrict__ ycur, const int* __restrict__ n_un,
    const int* __restrict__ ulist, const int* __restrict__ adj_s,
    const int* __restrict__ cnt_u, const float4* __restrict__ sconst,
    float4* __restrict__ out_y) {
    int g = blockIdx.x * 32 + threadIdx.x / 10;
    int l = threadIdx.x % 10;
    if (g >= *n_un) return;
    int u = ulist[g];
    int cu = cnt_u[u];
    int cnt = cu < CAPS ? cu : CAPS;
    const int* lst = adj_s + (size_t)u * CAPS;
    float4 s = sconst[(size_t)u * 10 + l];
    int e = 0;
    for (; e + 8 <= cnt; e += 8) {
        uint2 v[8];
#pragma unroll
        for (int q = 0; q < 8; q++) v[q] = ycur[(size_t)lst[e + q] * 10 + l];
#pragma unroll
        for (int q = 0; q < 8; q++) {
            s.x += bf_lo(v[q].x); s.y += bf_hi(v[q].x);
            s.z += bf_lo(v[q].y); s.w += bf_hi(v[q].y);
        }
    }
    for (; e + 4 <= cnt; e += 4) {
        uint2 v[4];
#pragma unroll
        for (int q = 0; q < 4; q++) v[q] = ycur[(size_t)lst[e + q] * 10 + l];
#pragma unroll
        for (int q = 0; q < 4; q++) {
            s.x += bf_lo(v[q].x); s.y += bf_hi(v[q].x);
            s.z += bf_lo(v[q].y); s.w += bf_hi(v[q].y);
        }
    }
    for (; e < cnt; e++) {
        uint2 v = ycur[(size_t)lst[e] * 10 + l];
        s.x += bf_lo(v.x); s.y += bf_hi(v.x);
        s.z += bf_lo(v.y); s.w += bf_hi(v.y);
    }
    out_y[(size_t)u * 10 + l] = s;
}

// ---------------------------------------------------------------------------
extern "C" void kernel_launch(void* const* d_in, const int* in_sizes, int n_in,
                              void* d_out, int out_size, void* d_ws, size_t ws_size,
                              hipStream_t stream) {
    const float* feat   = (const float*)d_in[0];
    const float* labels = (const float*)d_in[1];
    const void*  mask   = d_in[2];
    const int*   src    = (const int*)d_in[3];
    const int*   dst    = (const int*)d_in[4];
    const float* W1     = (const float*)d_in[5];
    const float* b1     = (const float*)d_in[6];
    const float* W2     = (const float*)d_in[7];
    const float* b2     = (const float*)d_in[8];

    float* out_x = (float*)d_out;
    float* out_y = out_x + (size_t)Nn * NC;

    char* ws = (char*)d_ws;
    size_t off = 0;
    auto alloc = [&](size_t bytes) -> void* {
        void* p = ws + off;
        off += (bytes + 255) & ~(size_t)255;
        return p;
    };
    // --- zeroed header ---
    int* flag    = (int*)alloc(256);   // flag[0]=fmt, flag[1]=n_un
    int* n_un    = flag + 1;
    int* cnt_src = (int*)alloc((size_t)Nn * 4);
    int* cur_d   = (int*)alloc(512);
    int* cur_s   = (int*)alloc(512);
    size_t zero_bytes = off;
    // --- non-zeroed ---
    int* cnt_dst = (int*)alloc((size_t)Nn * 4);
    int* cnt_u   = (int*)alloc((size_t)Nn * 4);
    int* cnt_m   = (int*)alloc((size_t)Nn * 4);
    int* ulist   = (int*)alloc((size_t)Nn * 4);
    unsigned short* W1t = (unsigned short*)alloc((size_t)HID * INF_ * 2); // 64KB
    // bins live concurrently with h1b (phase1 overlap) -> no aliasing
    unsigned* bkt_d = (unsigned*)alloc((size_t)NB * CAPB_D * 4);  // ~4.0MB
    unsigned* bkt_s = (unsigned*)alloc((size_t)NB * CAPB_S * 4);  // ~2.4MB
    unsigned short* h1b = (unsigned short*)alloc((size_t)Nn * HID * 2); // 12.8MB
    uint4* x1b = (uint4*)alloc((size_t)Nn * HID * 2);       // bf16 x1, 12.8MB
    int* adj_s   = (int*)alloc((size_t)Nn * CAPS * 4);
    int* adj_dst = (int*)alloc((size_t)Nn * CAPD * 4);
    unsigned* h2b = (unsigned*)alloc((size_t)Nn * NC * 2);  // bf16 h2
    float* sconst = (float*)alloc((size_t)Nn * NC * 4);
    uint2* y1b = (uint2*)alloc((size_t)Nn * NC * 2);        // bf16 y ping
    uint2* y2b = (uint2*)alloc((size_t)Nn * NC * 2);        // bf16 y pong

    hipMemsetAsync(d_ws, 0, zero_bytes, stream);

    detect_prep<<<49 + HID, 256, 0, stream>>>((const unsigned int*)mask, flag,
                                              W1, W1t);
    phase1<<<NBLK + G1BLK, 256, 0, stream>>>(
        src, dst, mask, flag, cnt_src, cur_d, cur_s, bkt_d, bkt_s,
        feat, W1t, h1b);
    build_csr_both<<<NB * 2 + SCB, 256, 0, stream>>>(
        bkt_d, cur_d, bkt_s, cur_s, mask, flag, cnt_src,
        adj_dst, cnt_dst, adj_s, cnt_u, cnt_m, n_un, ulist, h1b);

    // --- fused chains: agg1 ∥ iter1, gemm2 ∥ iter2, agg2 ∥ iter3 ---
    k_agg1_lconst<<<AGG1_BLKS + LPA_BLKS, 320, 0, stream>>>(
        (const uint4*)h1b, adj_dst, cnt_dst, (const float4*)b1, x1b,
        (const float4*)labels, mask, flag, n_un, ulist, adj_s,
        cnt_m, (float4*)sconst, y1b, (float4*)out_y);
    k_gemm2_mid<<<GEMM2_BLKS + LPA_BLKS, 320, 0, stream>>>(
        (const uint4*)x1b, (const float4*)W2, cnt_src, h2b,
        y1b, n_un, ulist, adj_s, cnt_u, (const float4*)sconst, y2b);
    k_agg2_mid<<<LPA_BLKS + LPA_BLKS, 320, 0, stream>>>(
        (const uint2*)h2b, adj_dst, cnt_dst, (const float4*)b2, (float4*)out_x,
        y2b, n_un, ulist, adj_s, cnt_u, (const float4*)sconst, y1b);

    // --- LPA iterations 4..9 (ping-pong), then 10 ---
    const uint2* cur = y1b;
    for (int i = 0; i < 6; i++) {
        uint2* nxt = (i & 1) ? y1b : y2b;
        lpa_mid<<<LPA_BLKS, 320, 0, stream>>>(
            cur, n_un, ulist, adj_s, cnt_u, (const float4*)sconst, nxt);
        cur = nxt;
    }
    lpa_last<<<LPA_BLKS, 320, 0, stream>>>(   // iteration 10, cur == y1b
        cur, n_un, ulist, adj_s, cnt_u, (const float4*)sconst, (float4*)out_y);
}